// Round 1
// baseline (1368.990 us; speedup 1.0000x reference)
//
#include <hip/hip_runtime.h>
#include <math.h>

#define NN 10000
#define EE 320000
#define TE 32
#define INV_AVG (1.0f / 565.0f)

// out layout (flat concat): positions[120000] | vectors[120000] | features[1280000] | skip[120000]
#define OUT_POS 0
#define OUT_VEC 120000
#define OUT_FEAT 240000
#define OUT_SKIP 1520000
#define OUT_TOTAL 1640000

__device__ __forceinline__ float siluf(float x) { return x / (1.0f + __expf(-x)); }

// D = silu(A @ W + bias). A: LDS [TE][AS]; W: global row-major [K][128]; D: LDS [TE][DS].
// 256 threads: thread -> 4 rows x 4 cols register tile.
template<int K, int AS, int DS>
__device__ __forceinline__ void mm_tile_silu(const float* Ald, float* Dld,
                                             const float* __restrict__ W,
                                             const float* __restrict__ bias, int t)
{
    const int tc = t & 31, tr = t >> 5;
    const int j = tc * 4, e0 = tr * 4;
    float acc[4][4];
#pragma unroll
    for (int i = 0; i < 4; ++i) { acc[i][0] = acc[i][1] = acc[i][2] = acc[i][3] = 0.0f; }
#pragma unroll 2
    for (int k = 0; k < K; k += 4) {
        float4 b0 = *(const float4*)(W + (k + 0) * 128 + j);
        float4 b1 = *(const float4*)(W + (k + 1) * 128 + j);
        float4 b2 = *(const float4*)(W + (k + 2) * 128 + j);
        float4 b3 = *(const float4*)(W + (k + 3) * 128 + j);
#pragma unroll
        for (int i = 0; i < 4; ++i) {
            float4 a = *(const float4*)(Ald + (e0 + i) * AS + k);
            acc[i][0] = fmaf(a.x, b0.x, acc[i][0]);
            acc[i][1] = fmaf(a.x, b0.y, acc[i][1]);
            acc[i][2] = fmaf(a.x, b0.z, acc[i][2]);
            acc[i][3] = fmaf(a.x, b0.w, acc[i][3]);
            acc[i][0] = fmaf(a.y, b1.x, acc[i][0]);
            acc[i][1] = fmaf(a.y, b1.y, acc[i][1]);
            acc[i][2] = fmaf(a.y, b1.z, acc[i][2]);
            acc[i][3] = fmaf(a.y, b1.w, acc[i][3]);
            acc[i][0] = fmaf(a.z, b2.x, acc[i][0]);
            acc[i][1] = fmaf(a.z, b2.y, acc[i][1]);
            acc[i][2] = fmaf(a.z, b2.z, acc[i][2]);
            acc[i][3] = fmaf(a.z, b2.w, acc[i][3]);
            acc[i][0] = fmaf(a.w, b3.x, acc[i][0]);
            acc[i][1] = fmaf(a.w, b3.y, acc[i][1]);
            acc[i][2] = fmaf(a.w, b3.z, acc[i][2]);
            acc[i][3] = fmaf(a.w, b3.w, acc[i][3]);
        }
    }
    float4 bv = *(const float4*)(bias + j);
#pragma unroll
    for (int i = 0; i < 4; ++i) {
        float4 o;
        o.x = siluf(acc[i][0] + bv.x);
        o.y = siluf(acc[i][1] + bv.y);
        o.z = siluf(acc[i][2] + bv.z);
        o.w = siluf(acc[i][3] + bv.w);
        *(float4*)(Dld + (e0 + i) * DS + j) = o;
    }
}

// head: p = tanh(h2 @ Wf), Wf [128][4], h2 in LDS stride AS. 256 threads:
// e = t>>3 (32 edges), v = (t>>1)&3, half = t&1 (split K).
template<int AS>
__device__ __forceinline__ void head_tanh(const float* Ald, const float* __restrict__ Wf,
                                          float* pxy, int base, int t)
{
    int e = t >> 3, v = (t >> 1) & 3, half = t & 1;
    const float* a = Ald + e * AS + half * 64;
    const float* w = Wf + half * 256 + v;
    float acc = 0.0f;
#pragma unroll 8
    for (int k = 0; k < 64; ++k) acc = fmaf(a[k], w[k * 4], acc);
    acc += __shfl_xor(acc, 1);
    if (!half) pxy[e * 8 + base + v] = tanhf(acc);
}

__global__ __launch_bounds__(256) void init_kernel(const float* __restrict__ pos,
                                                   float* __restrict__ out)
{
    int idx = blockIdx.x * 256 + threadIdx.x;
    if (idx < OUT_TOTAL) out[idx] = (idx < 120000) ? pos[idx] : 0.0f;
}

__global__ __launch_bounds__(256) void edge_kernel(
    const float* __restrict__ pos, const float* __restrict__ vec,
    const float* __restrict__ nf,
    const int* __restrict__ snd, const int* __restrict__ rcv,
    const float* __restrict__ We0, const float* __restrict__ be0,
    const float* __restrict__ We1, const float* __restrict__ be1,
    const float* __restrict__ Winf, const float* __restrict__ binf,
    const float* __restrict__ Wx0, const float* __restrict__ bx0,
    const float* __restrict__ Wx1, const float* __restrict__ bx1,
    const float* __restrict__ Wxf,
    const float* __restrict__ Wy0, const float* __restrict__ by0,
    const float* __restrict__ Wy1, const float* __restrict__ by1,
    const float* __restrict__ Wyf,
    float* outPos, float* outSkip, float* outFeat)
{
    __shared__ float A[TE * 268];      // ef [32][264+pad]; later reused for hx2/hy2
    __shared__ float B1[TE * 132];
    __shared__ float B2[TE * 132];     // m lives here
    __shared__ float dstore[TE * 24];  // per edge: dxn[12], dyn[12]
    __shared__ float pxy[TE * 8];      // px[4], py[4]
    __shared__ float gatev[TE];
    __shared__ int sidx[TE], ridx[TE];

    const int t = threadIdx.x;
    const int e_base = blockIdx.x * TE;

    if (t < TE) { sidx[t] = snd[e_base + t]; ridx[t] = rcv[e_base + t]; }
    __syncthreads();

    // gather node features into ef[:, 0:256]
#pragma unroll
    for (int it = 0; it < 8; ++it) {
        int idx = t + it * 256;          // 0..2047
        int row = idx >> 5;              // 0..63
        int q = idx & 31;
        int e = row >> 1, half = row & 1;
        int node = half ? ridx[e] : sidx[e];
        float4 v4 = *(const float4*)(nf + node * 128 + q * 4);
        *(float4*)(A + e * 268 + half * 128 + q * 4) = v4;
    }
    // radial: 32 edges x {pos,vec} x 4 vectors = 256 tasks
    {
        int e = t >> 3, sub = t & 7;
        int tensor = sub >> 2, v = sub & 3;
        const float* c = tensor ? vec : pos;
        int si = sidx[e] * 12 + v * 3, ri = ridx[e] * 12 + v * 3;
        float d0 = c[ri + 0] - c[si + 0];
        float d1 = c[ri + 1] - c[si + 1];
        float d2 = c[ri + 2] - c[si + 2];
        float ss = fmaf(d0, d0, fmaf(d1, d1, d2 * d2)) + 1e-8f;
        float l = sqrtf(ss);
        float inv = 1.0f / (1.0f + l);
        A[e * 268 + 256 + tensor * 4 + v] = ss;   // l^2 (= ss exactly)
        dstore[e * 24 + tensor * 12 + v * 3 + 0] = d0 * inv;
        dstore[e * 24 + tensor * 12 + v * 3 + 1] = d1 * inv;
        dstore[e * 24 + tensor * 12 + v * 3 + 2] = d2 * inv;
    }
    __syncthreads();

    mm_tile_silu<264, 268, 132>(A, B1, We0, be0, t);   // h0
    __syncthreads();
    mm_tile_silu<128, 132, 132>(B1, B2, We1, be1, t);  // m
    __syncthreads();
    mm_tile_silu<128, 132, 132>(B2, B1, Wx0, bx0, t);  // hx
    __syncthreads();
    mm_tile_silu<128, 132, 268>(B1, A, Wx1, bx1, t);   // hx2 -> A
    __syncthreads();
    head_tanh<268>(A, Wxf, pxy, 0, t);                 // px
    __syncthreads();
    mm_tile_silu<128, 132, 132>(B2, B1, Wy0, by0, t);  // hy
    __syncthreads();
    mm_tile_silu<128, 132, 268>(B1, A, Wy1, by1, t);   // hy2 -> A
    __syncthreads();
    head_tanh<268>(A, Wyf, pxy, 4, t);                 // py
    // gate = sigmoid(m @ Winf + binf): e = t>>3, seg = t&7 (16 k each)
    {
        int e = t >> 3, seg = t & 7;
        const float* mrow = B2 + e * 132 + seg * 16;
        const float* w = Winf + seg * 16;
        float acc = 0.0f;
#pragma unroll
        for (int k = 0; k < 16; ++k) acc = fmaf(mrow[k], w[k], acc);
        acc += __shfl_xor(acc, 1);
        acc += __shfl_xor(acc, 2);
        acc += __shfl_xor(acc, 4);
        if (!seg) gatev[e] = 1.0f / (1.0f + __expf(-(acc + binf[0])));
    }
    __syncthreads();

    // scatter gated messages: 32 edges x 128 = 4096 atomics
#pragma unroll
    for (int it = 0; it < 16; ++it) {
        int idx = t + it * 256;
        int e = idx >> 7, jj = idx & 127;
        float val = B2[e * 132 + jj] * gatev[e] * INV_AVG;
        atomicAdd(outFeat + ridx[e] * 128 + jj, val);
    }
    // scatter shifts: 32 edges x 24 = 768 atomics
#pragma unroll
    for (int it = 0; it < 3; ++it) {
        int idx = t + it * 256;
        int e = idx / 24, c = idx - e * 24;
        int tensor = (c >= 12) ? 1 : 0;
        int rem = c - tensor * 12;
        int v = rem / 3;
        float val = dstore[e * 24 + c] * pxy[e * 8 + tensor * 4 + v] * INV_AVG;
        float* dst = tensor ? outSkip : outPos;
        atomicAdd(dst + ridx[e] * 12 + rem, val);
    }
}

__global__ __launch_bounds__(256) void node_kernel(
    const float* __restrict__ nf, const float* __restrict__ nvec,
    const float* __restrict__ Wh0, const float* __restrict__ bh0,
    const float* __restrict__ Wh1, const float* __restrict__ bh1,
    const float* __restrict__ Wh2, const float* __restrict__ bh2,
    float* outFeat /* holds m_i on entry */, float* outVec,
    const float* __restrict__ outSkip)
{
    __shared__ float A[TE * 260];   // hin [32][256+pad]
    __shared__ float B1[TE * 132];
    __shared__ float B2[TE * 132];
    const int t = threadIdx.x;
    const int n_base = blockIdx.x * TE;

#pragma unroll
    for (int it = 0; it < 8; ++it) {
        int idx = t + it * 256;
        int row = idx >> 5, q = idx & 31;
        int i = row >> 1, half = row & 1;
        int n = n_base + i;
        float4 v4 = make_float4(0.f, 0.f, 0.f, 0.f);
        if (n < NN) v4 = *(const float4*)((half ? nf : (const float*)outFeat) + n * 128 + q * 4);
        *(float4*)(A + i * 260 + half * 128 + q * 4) = v4;
    }
    __syncthreads();
    mm_tile_silu<256, 260, 132>(A, B1, Wh0, bh0, t);
    __syncthreads();
    mm_tile_silu<128, 132, 132>(B1, B2, Wh1, bh1, t);
    __syncthreads();
    // final: out = h2 @ Wh2 + bh2 + nf  (no activation), write global
    {
        const int tc = t & 31, tr = t >> 5;
        const int j = tc * 4, i0 = tr * 4;
        float acc[4][4];
#pragma unroll
        for (int i = 0; i < 4; ++i) { acc[i][0] = acc[i][1] = acc[i][2] = acc[i][3] = 0.0f; }
#pragma unroll 2
        for (int k = 0; k < 128; k += 4) {
            float4 b0 = *(const float4*)(Wh2 + (k + 0) * 128 + j);
            float4 b1 = *(const float4*)(Wh2 + (k + 1) * 128 + j);
            float4 b2 = *(const float4*)(Wh2 + (k + 2) * 128 + j);
            float4 b3 = *(const float4*)(Wh2 + (k + 3) * 128 + j);
#pragma unroll
            for (int i = 0; i < 4; ++i) {
                float4 a = *(const float4*)(B2 + (i0 + i) * 132 + k);
                acc[i][0] = fmaf(a.x, b0.x, acc[i][0]);
                acc[i][1] = fmaf(a.x, b0.y, acc[i][1]);
                acc[i][2] = fmaf(a.x, b0.z, acc[i][2]);
                acc[i][3] = fmaf(a.x, b0.w, acc[i][3]);
                acc[i][0] = fmaf(a.y, b1.x, acc[i][0]);
                acc[i][1] = fmaf(a.y, b1.y, acc[i][1]);
                acc[i][2] = fmaf(a.y, b1.z, acc[i][2]);
                acc[i][3] = fmaf(a.y, b1.w, acc[i][3]);
                acc[i][0] = fmaf(a.z, b2.x, acc[i][0]);
                acc[i][1] = fmaf(a.z, b2.y, acc[i][1]);
                acc[i][2] = fmaf(a.z, b2.z, acc[i][2]);
                acc[i][3] = fmaf(a.z, b2.w, acc[i][3]);
                acc[i][0] = fmaf(a.w, b3.x, acc[i][0]);
                acc[i][1] = fmaf(a.w, b3.y, acc[i][1]);
                acc[i][2] = fmaf(a.w, b3.z, acc[i][2]);
                acc[i][3] = fmaf(a.w, b3.w, acc[i][3]);
            }
        }
        float4 bv = *(const float4*)(bh2 + j);
#pragma unroll
        for (int i = 0; i < 4; ++i) {
            int n = n_base + i0 + i;
            if (n < NN) {
                float4 r = *(const float4*)(nf + n * 128 + j);
                float4 o;
                o.x = acc[i][0] + bv.x + r.x;
                o.y = acc[i][1] + bv.y + r.y;
                o.z = acc[i][2] + bv.z + r.z;
                o.w = acc[i][3] + bv.w + r.w;
                *(float4*)(outFeat + n * 128 + j) = o;
            }
        }
    }
    // vectors_out = skip + node_vectors : 32 nodes x 12
    {
        int idx = t;
        if (idx < TE * 12) {
            int n = n_base + idx / 12;
            if (n < NN) {
                int g = n_base * 12 + idx;
                outVec[g] = outSkip[g] + nvec[g];
            }
        }
        idx = t + 256;
        if (idx < TE * 12) {
            int n = n_base + idx / 12;
            if (n < NN) {
                int g = n_base * 12 + idx;
                outVec[g] = outSkip[g] + nvec[g];
            }
        }
    }
}

extern "C" void kernel_launch(void* const* d_in, const int* in_sizes, int n_in,
                              void* d_out, int out_size, void* d_ws, size_t ws_size,
                              hipStream_t stream)
{
    (void)in_sizes; (void)n_in; (void)out_size; (void)d_ws; (void)ws_size;

    const float* pos  = (const float*)d_in[0];
    const float* vecv = (const float*)d_in[1];
    const float* nf   = (const float*)d_in[2];
    const int*   snd  = (const int*)d_in[3];
    const int*   rcv  = (const int*)d_in[4];
    const float* We0  = (const float*)d_in[5];
    const float* be0  = (const float*)d_in[6];
    const float* We1  = (const float*)d_in[7];
    const float* be1  = (const float*)d_in[8];
    const float* Winf = (const float*)d_in[9];
    const float* binf = (const float*)d_in[10];
    const float* Wx0  = (const float*)d_in[11];
    const float* bx0  = (const float*)d_in[12];
    const float* Wx1  = (const float*)d_in[13];
    const float* bx1  = (const float*)d_in[14];
    const float* Wxf  = (const float*)d_in[15];
    const float* Wy0  = (const float*)d_in[16];
    const float* by0  = (const float*)d_in[17];
    const float* Wy1  = (const float*)d_in[18];
    const float* by1  = (const float*)d_in[19];
    const float* Wyf  = (const float*)d_in[20];
    const float* Wh0  = (const float*)d_in[21];
    const float* bh0  = (const float*)d_in[22];
    const float* Wh1  = (const float*)d_in[23];
    const float* bh1  = (const float*)d_in[24];
    const float* Wh2  = (const float*)d_in[25];
    const float* bh2  = (const float*)d_in[26];

    float* out     = (float*)d_out;
    float* outPos  = out + OUT_POS;
    float* outVec  = out + OUT_VEC;
    float* outFeat = out + OUT_FEAT;
    float* outSkip = out + OUT_SKIP;

    init_kernel<<<(OUT_TOTAL + 255) / 256, 256, 0, stream>>>(pos, out);

    edge_kernel<<<EE / TE, 256, 0, stream>>>(
        pos, vecv, nf, snd, rcv,
        We0, be0, We1, be1, Winf, binf,
        Wx0, bx0, Wx1, bx1, Wxf,
        Wy0, by0, Wy1, by1, Wyf,
        outPos, outSkip, outFeat);

    node_kernel<<<(NN + TE - 1) / TE, 256, 0, stream>>>(
        nf, vecv, Wh0, bh0, Wh1, bh1, Wh2, bh2,
        outFeat, outVec, outSkip);
}

// Round 2
// 410.452 us; speedup vs baseline: 3.3353x; 3.3353x over previous
//
#include <hip/hip_runtime.h>
#include <math.h>

#define NN 10000
#define EE 320000
#define TE 32
#define INV_AVG (1.0f / 565.0f)

// out layout (flat concat): positions[120000] | vectors[120000] | features[1280000] | skip[120000]
#define OUT_POS 0
#define OUT_VEC 120000
#define OUT_FEAT 240000
#define OUT_SKIP 1520000
#define OUT_TOTAL 1640000

// d_ws layout in ushort (bf16) elements: weight fragments in MFMA A-operand order
// frag[kc][oc_tile][lane][8] ; element j = W[kc*32 + (lane>>4)*8 + j][oc_tile*16 + (lane&15)]
#define WS_WE0 0                      // [9][8][64][8]  = 36864 (K padded 264->288)
#define WS_WE1 36864                  // [4][8][64][8]  = 16384 each below
#define WS_WX0 (36864 + 16384)
#define WS_WX1 (36864 + 2 * 16384)
#define WS_WY0 (36864 + 3 * 16384)
#define WS_WY1 (36864 + 4 * 16384)
#define WS_TOTAL (36864 + 5 * 16384)  // 118784 ushorts = 237568 bytes

typedef __attribute__((ext_vector_type(8))) short bfrag;
typedef __attribute__((ext_vector_type(4))) float f4acc;

__device__ __forceinline__ float siluf(float x) { return x / (1.0f + __expf(-x)); }

__device__ __forceinline__ unsigned short f2bf(float x) {
    union { float f; unsigned int u; } c; c.f = x;
    unsigned int r = c.u + 0x7FFFu + ((c.u >> 16) & 1u);   // RNE
    return (unsigned short)(r >> 16);
}
__device__ __forceinline__ float bf2f(unsigned short h) {
    union { unsigned int u; float f; } c; c.u = ((unsigned int)h) << 16; return c.f;
}

// ---------------- weight prep: fp32 -> bf16 fragment layout in ws ----------------
__global__ __launch_bounds__(256) void prep_weights(
    const float* __restrict__ We0, const float* __restrict__ We1,
    const float* __restrict__ Wx0, const float* __restrict__ Wx1,
    const float* __restrict__ Wy0, const float* __restrict__ Wy1,
    unsigned short* __restrict__ wsW)
{
    int tid = blockIdx.x * 256 + threadIdx.x;
    if (tid >= 4608 + 5 * 2048) return;
    const float* W; unsigned short* dst; int Kact, rel;
    if (tid < 4608) { W = We0; dst = wsW + WS_WE0; Kact = 264; rel = tid; }
    else {
        int r = tid - 4608; int m = r >> 11; rel = r & 2047; Kact = 128;
        switch (m) {
            case 0: W = We1; dst = wsW + WS_WE1; break;
            case 1: W = Wx0; dst = wsW + WS_WX0; break;
            case 2: W = Wx1; dst = wsW + WS_WX1; break;
            case 3: W = Wy0; dst = wsW + WS_WY0; break;
            default: W = Wy1; dst = wsW + WS_WY1; break;
        }
    }
    int lane = rel & 63, oc = (rel >> 6) & 7, kc = rel >> 9;
    int k0 = kc * 32 + ((lane >> 4) << 3);
    int col = oc * 16 + (lane & 15);
    unsigned short* o = dst + (((kc * 8 + oc) * 64 + lane) << 3);
#pragma unroll
    for (int j = 0; j < 8; ++j) {
        int k = k0 + j;
        o[j] = (k < Kact) ? f2bf(W[k * 128 + col]) : (unsigned short)0;
    }
}

// ---------------- MFMA layer: D[32e][128ch] = silu(Act[32e][K] @ W[K][128] + b) ----------
// A operand = weight fragments (out-channels on M), B operand = LDS activations (edges on N).
template<int KC, int BSTRIDE>
__device__ __forceinline__ void mfma_layer(
    const unsigned short* __restrict__ fragW,
    const float* __restrict__ bias,
    const unsigned short* Bld,          // LDS [32][BSTRIDE] bf16
    unsigned short* Dld,                // LDS [32][136] bf16
    int t)
{
    const int lane = t & 63, w = t >> 6;
    const int mt0 = w * 2;
    const int lhi = lane >> 4, llo = lane & 15;
    f4acc acc00 = {0.f,0.f,0.f,0.f}, acc01 = acc00, acc10 = acc00, acc11 = acc00;
#pragma unroll
    for (int kc = 0; kc < KC; ++kc) {
        bfrag a0 = *(const bfrag*)(fragW + (((kc * 8 + mt0 + 0) * 64 + lane) << 3));
        bfrag a1 = *(const bfrag*)(fragW + (((kc * 8 + mt0 + 1) * 64 + lane) << 3));
        bfrag b0 = *(const bfrag*)(Bld + (llo)      * BSTRIDE + kc * 32 + lhi * 8);
        bfrag b1 = *(const bfrag*)(Bld + (16 + llo) * BSTRIDE + kc * 32 + lhi * 8);
        acc00 = __builtin_amdgcn_mfma_f32_16x16x32_bf16(a0, b0, acc00, 0, 0, 0);
        acc01 = __builtin_amdgcn_mfma_f32_16x16x32_bf16(a0, b1, acc01, 0, 0, 0);
        acc10 = __builtin_amdgcn_mfma_f32_16x16x32_bf16(a1, b0, acc10, 0, 0, 0);
        acc11 = __builtin_amdgcn_mfma_f32_16x16x32_bf16(a1, b1, acc11, 0, 0, 0);
    }
#pragma unroll
    for (int mi = 0; mi < 2; ++mi) {
        int ch = (mt0 + mi) * 16 + lhi * 4;
        float4 bv = *(const float4*)(bias + ch);
#pragma unroll
        for (int nt = 0; nt < 2; ++nt) {
            f4acc a = mi == 0 ? (nt == 0 ? acc00 : acc01) : (nt == 0 ? acc10 : acc11);
            int e = nt * 16 + llo;
            float v0 = siluf(a[0] + bv.x);
            float v1 = siluf(a[1] + bv.y);
            float v2 = siluf(a[2] + bv.z);
            float v3 = siluf(a[3] + bv.w);
            uint2 pk;
            pk.x = (unsigned int)f2bf(v0) | ((unsigned int)f2bf(v1) << 16);
            pk.y = (unsigned int)f2bf(v2) | ((unsigned int)f2bf(v3) << 16);
            *(uint2*)(Dld + e * 136 + ch) = pk;
        }
    }
}

// head: p = tanh(h2 @ Wf), Wf [128][4] fp32, h2 bf16 in LDS stride AS
template<int AS>
__device__ __forceinline__ void head_tanh_bf(const unsigned short* Ald,
                                             const float* __restrict__ Wf,
                                             float* pxy, int base, int t)
{
    int e = t >> 3, v = (t >> 1) & 3, half = t & 1;
    const unsigned short* a = Ald + e * AS + half * 64;
    const float* w = Wf + half * 256 + v;
    float acc = 0.0f;
#pragma unroll 8
    for (int k = 0; k < 64; ++k) acc = fmaf(bf2f(a[k]), w[k * 4], acc);
    acc += __shfl_xor(acc, 1);
    if (!half) pxy[e * 8 + base + v] = tanhf(acc);
}

__global__ __launch_bounds__(256) void init_kernel(const float* __restrict__ pos,
                                                   float* __restrict__ out)
{
    int idx = blockIdx.x * 256 + threadIdx.x;
    if (idx < OUT_TOTAL) out[idx] = (idx < 120000) ? pos[idx] : 0.0f;
}

__global__ __launch_bounds__(256) void edge_kernel(
    const float* __restrict__ pos, const float* __restrict__ vec,
    const float* __restrict__ nf,
    const int* __restrict__ snd, const int* __restrict__ rcv,
    const unsigned short* __restrict__ wsW,
    const float* __restrict__ be0, const float* __restrict__ be1,
    const float* __restrict__ Winf, const float* __restrict__ binf,
    const float* __restrict__ bx0, const float* __restrict__ bx1,
    const float* __restrict__ Wxf,
    const float* __restrict__ by0, const float* __restrict__ by1,
    const float* __restrict__ Wyf,
    float* outPos, float* outSkip, float* outFeat)
{
    __shared__ unsigned short EF[TE * 296];  // ef bf16 [32][288+8]; reused for hx2/hy2 (stride 136)
    __shared__ unsigned short H0[TE * 136];  // h0, then hx, then hy
    __shared__ unsigned short Mm[TE * 136];  // m (message)
    __shared__ float dstore[TE * 24];        // dxn[12], dyn[12] per edge (fp32)
    __shared__ float pxy[TE * 8];
    __shared__ float gatev[TE];
    __shared__ int sidx[TE], ridx[TE];

    const int t = threadIdx.x;
    const int e_base = blockIdx.x * TE;

    if (t < TE) { sidx[t] = snd[e_base + t]; ridx[t] = rcv[e_base + t]; }
    __syncthreads();

    // gather node features -> bf16 ef[:, 0:256]
#pragma unroll
    for (int it = 0; it < 8; ++it) {
        int idx = t + it * 256;          // 0..2047
        int row = idx >> 5;              // 0..63
        int q = idx & 31;
        int e = row >> 1, half = row & 1;
        int node = half ? ridx[e] : sidx[e];
        float4 v4 = *(const float4*)(nf + node * 128 + q * 4);
        uint2 pk;
        pk.x = (unsigned int)f2bf(v4.x) | ((unsigned int)f2bf(v4.y) << 16);
        pk.y = (unsigned int)f2bf(v4.z) | ((unsigned int)f2bf(v4.w) << 16);
        *(uint2*)(EF + e * 296 + half * 128 + q * 4) = pk;
    }
    // radial + K-pad zeroing: 32 edges x 8 subtasks
    {
        int e = t >> 3, sub = t & 7;
        int tensor = sub >> 2, v = sub & 3;
        const float* c = tensor ? vec : pos;
        int si = sidx[e] * 12 + v * 3, ri = ridx[e] * 12 + v * 3;
        float d0 = c[ri + 0] - c[si + 0];
        float d1 = c[ri + 1] - c[si + 1];
        float d2 = c[ri + 2] - c[si + 2];
        float ss = fmaf(d0, d0, fmaf(d1, d1, d2 * d2)) + 1e-8f;
        float l = sqrtf(ss);
        float inv = 1.0f / (1.0f + l);
        EF[e * 296 + 256 + tensor * 4 + v] = f2bf(ss);     // l^2
        dstore[e * 24 + tensor * 12 + v * 3 + 0] = d0 * inv;
        dstore[e * 24 + tensor * 12 + v * 3 + 1] = d1 * inv;
        dstore[e * 24 + tensor * 12 + v * 3 + 2] = d2 * inv;
#pragma unroll
        for (int z = 0; z < 3; ++z) EF[e * 296 + 264 + sub * 3 + z] = 0;  // zero pad k=264..287
    }
    __syncthreads();

    mfma_layer<9, 296>(wsW + WS_WE0, be0, EF, H0, t);  __syncthreads();  // h0
    mfma_layer<4, 136>(wsW + WS_WE1, be1, H0, Mm, t);  __syncthreads();  // m
    mfma_layer<4, 136>(wsW + WS_WX0, bx0, Mm, H0, t);  __syncthreads();  // hx
    mfma_layer<4, 136>(wsW + WS_WX1, bx1, H0, EF, t);  __syncthreads();  // hx2 -> EF
    head_tanh_bf<136>(EF, Wxf, pxy, 0, t);                               // px
    // gate = sigmoid(m @ Winf + binf)
    {
        int e = t >> 3, seg = t & 7;
        const unsigned short* mrow = Mm + e * 136 + seg * 16;
        const float* w = Winf + seg * 16;
        float acc = 0.0f;
#pragma unroll
        for (int k = 0; k < 16; ++k) acc = fmaf(bf2f(mrow[k]), w[k], acc);
        acc += __shfl_xor(acc, 1);
        acc += __shfl_xor(acc, 2);
        acc += __shfl_xor(acc, 4);
        if (!seg) gatev[e] = 1.0f / (1.0f + __expf(-(acc + binf[0])));
    }
    __syncthreads();
    mfma_layer<4, 136>(wsW + WS_WY0, by0, Mm, H0, t);  __syncthreads();  // hy
    mfma_layer<4, 136>(wsW + WS_WY1, by1, H0, EF, t);  __syncthreads();  // hy2 -> EF
    head_tanh_bf<136>(EF, Wyf, pxy, 4, t);                               // py
    __syncthreads();

    // scatter gated messages: 32 edges x 128
#pragma unroll
    for (int it = 0; it < 16; ++it) {
        int idx = t + it * 256;
        int e = idx >> 7, jj = idx & 127;
        float val = bf2f(Mm[e * 136 + jj]) * gatev[e] * INV_AVG;
        atomicAdd(outFeat + ridx[e] * 128 + jj, val);
    }
    // scatter shifts: 32 edges x 24
#pragma unroll
    for (int it = 0; it < 3; ++it) {
        int idx = t + it * 256;
        int e = idx / 24, c = idx - e * 24;
        int tensor = (c >= 12) ? 1 : 0;
        int rem = c - tensor * 12;
        int v = rem / 3;
        float val = dstore[e * 24 + c] * pxy[e * 8 + tensor * 4 + v] * INV_AVG;
        float* dst = tensor ? outSkip : outPos;
        atomicAdd(dst + ridx[e] * 12 + rem, val);
    }
}

// ---------------- node kernel (fp32, unchanged — 3% of FLOPs) ----------------
template<int K, int AS, int DS>
__device__ __forceinline__ void mm_tile_silu(const float* Ald, float* Dld,
                                             const float* __restrict__ W,
                                             const float* __restrict__ bias, int t)
{
    const int tc = t & 31, tr = t >> 5;
    const int j = tc * 4, e0 = tr * 4;
    float acc[4][4];
#pragma unroll
    for (int i = 0; i < 4; ++i) { acc[i][0] = acc[i][1] = acc[i][2] = acc[i][3] = 0.0f; }
#pragma unroll 2
    for (int k = 0; k < K; k += 4) {
        float4 b0 = *(const float4*)(W + (k + 0) * 128 + j);
        float4 b1 = *(const float4*)(W + (k + 1) * 128 + j);
        float4 b2 = *(const float4*)(W + (k + 2) * 128 + j);
        float4 b3 = *(const float4*)(W + (k + 3) * 128 + j);
#pragma unroll
        for (int i = 0; i < 4; ++i) {
            float4 a = *(const float4*)(Ald + (e0 + i) * AS + k);
            acc[i][0] = fmaf(a.x, b0.x, acc[i][0]);
            acc[i][1] = fmaf(a.x, b0.y, acc[i][1]);
            acc[i][2] = fmaf(a.x, b0.z, acc[i][2]);
            acc[i][3] = fmaf(a.x, b0.w, acc[i][3]);
            acc[i][0] = fmaf(a.y, b1.x, acc[i][0]);
            acc[i][1] = fmaf(a.y, b1.y, acc[i][1]);
            acc[i][2] = fmaf(a.y, b1.z, acc[i][2]);
            acc[i][3] = fmaf(a.y, b1.w, acc[i][3]);
            acc[i][0] = fmaf(a.z, b2.x, acc[i][0]);
            acc[i][1] = fmaf(a.z, b2.y, acc[i][1]);
            acc[i][2] = fmaf(a.z, b2.z, acc[i][2]);
            acc[i][3] = fmaf(a.z, b2.w, acc[i][3]);
            acc[i][0] = fmaf(a.w, b3.x, acc[i][0]);
            acc[i][1] = fmaf(a.w, b3.y, acc[i][1]);
            acc[i][2] = fmaf(a.w, b3.z, acc[i][2]);
            acc[i][3] = fmaf(a.w, b3.w, acc[i][3]);
        }
    }
    float4 bv = *(const float4*)(bias + j);
#pragma unroll
    for (int i = 0; i < 4; ++i) {
        float4 o;
        o.x = siluf(acc[i][0] + bv.x);
        o.y = siluf(acc[i][1] + bv.y);
        o.z = siluf(acc[i][2] + bv.z);
        o.w = siluf(acc[i][3] + bv.w);
        *(float4*)(Dld + (e0 + i) * DS + j) = o;
    }
}

__global__ __launch_bounds__(256) void node_kernel(
    const float* __restrict__ nf, const float* __restrict__ nvec,
    const float* __restrict__ Wh0, const float* __restrict__ bh0,
    const float* __restrict__ Wh1, const float* __restrict__ bh1,
    const float* __restrict__ Wh2, const float* __restrict__ bh2,
    float* outFeat /* holds m_i on entry */, float* outVec,
    const float* __restrict__ outSkip)
{
    __shared__ float A[TE * 260];
    __shared__ float B1[TE * 132];
    __shared__ float B2[TE * 132];
    const int t = threadIdx.x;
    const int n_base = blockIdx.x * TE;

#pragma unroll
    for (int it = 0; it < 8; ++it) {
        int idx = t + it * 256;
        int row = idx >> 5, q = idx & 31;
        int i = row >> 1, half = row & 1;
        int n = n_base + i;
        float4 v4 = make_float4(0.f, 0.f, 0.f, 0.f);
        if (n < NN) v4 = *(const float4*)((half ? nf : (const float*)outFeat) + n * 128 + q * 4);
        *(float4*)(A + i * 260 + half * 128 + q * 4) = v4;
    }
    __syncthreads();
    mm_tile_silu<256, 260, 132>(A, B1, Wh0, bh0, t);
    __syncthreads();
    mm_tile_silu<128, 132, 132>(B1, B2, Wh1, bh1, t);
    __syncthreads();
    {
        const int tc = t & 31, tr = t >> 5;
        const int j = tc * 4, i0 = tr * 4;
        float acc[4][4];
#pragma unroll
        for (int i = 0; i < 4; ++i) { acc[i][0] = acc[i][1] = acc[i][2] = acc[i][3] = 0.0f; }
#pragma unroll 2
        for (int k = 0; k < 128; k += 4) {
            float4 b0 = *(const float4*)(Wh2 + (k + 0) * 128 + j);
            float4 b1 = *(const float4*)(Wh2 + (k + 1) * 128 + j);
            float4 b2 = *(const float4*)(Wh2 + (k + 2) * 128 + j);
            float4 b3 = *(const float4*)(Wh2 + (k + 3) * 128 + j);
#pragma unroll
            for (int i = 0; i < 4; ++i) {
                float4 a = *(const float4*)(B2 + (i0 + i) * 132 + k);
                acc[i][0] = fmaf(a.x, b0.x, acc[i][0]);
                acc[i][1] = fmaf(a.x, b0.y, acc[i][1]);
                acc[i][2] = fmaf(a.x, b0.z, acc[i][2]);
                acc[i][3] = fmaf(a.x, b0.w, acc[i][3]);
                acc[i][0] = fmaf(a.y, b1.x, acc[i][0]);
                acc[i][1] = fmaf(a.y, b1.y, acc[i][1]);
                acc[i][2] = fmaf(a.y, b1.z, acc[i][2]);
                acc[i][3] = fmaf(a.y, b1.w, acc[i][3]);
                acc[i][0] = fmaf(a.z, b2.x, acc[i][0]);
                acc[i][1] = fmaf(a.z, b2.y, acc[i][1]);
                acc[i][2] = fmaf(a.z, b2.z, acc[i][2]);
                acc[i][3] = fmaf(a.z, b2.w, acc[i][3]);
                acc[i][0] = fmaf(a.w, b3.x, acc[i][0]);
                acc[i][1] = fmaf(a.w, b3.y, acc[i][1]);
                acc[i][2] = fmaf(a.w, b3.z, acc[i][2]);
                acc[i][3] = fmaf(a.w, b3.w, acc[i][3]);
            }
        }
        float4 bv = *(const float4*)(bh2 + j);
#pragma unroll
        for (int i = 0; i < 4; ++i) {
            int n = n_base + i0 + i;
            if (n < NN) {
                float4 r = *(const float4*)(nf + n * 128 + j);
                float4 o;
                o.x = acc[i][0] + bv.x + r.x;
                o.y = acc[i][1] + bv.y + r.y;
                o.z = acc[i][2] + bv.z + r.z;
                o.w = acc[i][3] + bv.w + r.w;
                *(float4*)(outFeat + n * 128 + j) = o;
            }
        }
    }
    {
        int idx = t;
        if (idx < TE * 12) {
            int n = n_base + idx / 12;
            if (n < NN) {
                int g = n_base * 12 + idx;
                outVec[g] = outSkip[g] + nvec[g];
            }
        }
        idx = t + 256;
        if (idx < TE * 12) {
            int n = n_base + idx / 12;
            if (n < NN) {
                int g = n_base * 12 + idx;
                outVec[g] = outSkip[g] + nvec[g];
            }
        }
    }
}

extern "C" void kernel_launch(void* const* d_in, const int* in_sizes, int n_in,
                              void* d_out, int out_size, void* d_ws, size_t ws_size,
                              hipStream_t stream)
{
    (void)in_sizes; (void)n_in; (void)out_size; (void)ws_size;

    const float* pos  = (const float*)d_in[0];
    const float* vecv = (const float*)d_in[1];
    const float* nf   = (const float*)d_in[2];
    const int*   snd  = (const int*)d_in[3];
    const int*   rcv  = (const int*)d_in[4];
    const float* We0  = (const float*)d_in[5];
    const float* be0  = (const float*)d_in[6];
    const float* We1  = (const float*)d_in[7];
    const float* be1  = (const float*)d_in[8];
    const float* Winf = (const float*)d_in[9];
    const float* binf = (const float*)d_in[10];
    const float* Wx0  = (const float*)d_in[11];
    const float* bx0  = (const float*)d_in[12];
    const float* Wx1  = (const float*)d_in[13];
    const float* bx1  = (const float*)d_in[14];
    const float* Wxf  = (const float*)d_in[15];
    const float* Wy0  = (const float*)d_in[16];
    const float* by0  = (const float*)d_in[17];
    const float* Wy1  = (const float*)d_in[18];
    const float* by1  = (const float*)d_in[19];
    const float* Wyf  = (const float*)d_in[20];
    const float* Wh0  = (const float*)d_in[21];
    const float* bh0  = (const float*)d_in[22];
    const float* Wh1  = (const float*)d_in[23];
    const float* bh1  = (const float*)d_in[24];
    const float* Wh2  = (const float*)d_in[25];
    const float* bh2  = (const float*)d_in[26];

    float* out     = (float*)d_out;
    float* outPos  = out + OUT_POS;
    float* outVec  = out + OUT_VEC;
    float* outFeat = out + OUT_FEAT;
    float* outSkip = out + OUT_SKIP;
    unsigned short* wsW = (unsigned short*)d_ws;

    init_kernel<<<(OUT_TOTAL + 255) / 256, 256, 0, stream>>>(pos, out);

    prep_weights<<<(4608 + 5 * 2048 + 255) / 256, 256, 0, stream>>>(
        We0, We1, Wx0, Wx1, Wy0, Wy1, wsW);

    edge_kernel<<<EE / TE, 256, 0, stream>>>(
        pos, vecv, nf, snd, rcv, wsW,
        be0, be1, Winf, binf,
        bx0, bx1, Wxf,
        by0, by1, Wyf,
        outPos, outSkip, outFeat);

    node_kernel<<<(NN + TE - 1) / TE, 256, 0, stream>>>(
        nf, vecv, Wh0, bh0, Wh1, bh1, Wh2, bh2,
        outFeat, outVec, outSkip);
}